// Round 2
// baseline (276.839 us; speedup 1.0000x reference)
//
#include <hip/hip_runtime.h>

#define NBLOCKS 2048
#define NTHREADS 256

__global__ __launch_bounds__(NTHREADS) void loss1_partial(
    const float* __restrict__ x, const float* __restrict__ y,
    long long n, float* __restrict__ psum, int* __restrict__ pcnt) {
    long long tid = (long long)blockIdx.x * blockDim.x + threadIdx.x;
    long long stride = (long long)gridDim.x * blockDim.x;
    long long nvec = n >> 2;  // n = 32*1024*1024, divisible by 4

    const float4* __restrict__ x4 = (const float4*)x;
    const float4* __restrict__ y4 = (const float4*)y;

    float s = 0.0f;
    int c = 0;

    // Unroll-by-4 grid-stride: 8 independent 16B loads in flight per thread
    // (VGPR ~40) -> covers HBM latency; the 12-VGPR un-unrolled version was
    // latency-bound at 2.66 TB/s.
    long long i = tid;
    for (; i + 3 * stride < nvec; i += 4 * stride) {
        float4 a0 = x4[i];
        float4 a1 = x4[i + stride];
        float4 a2 = x4[i + 2 * stride];
        float4 a3 = x4[i + 3 * stride];
        float4 b0 = y4[i];
        float4 b1 = y4[i + stride];
        float4 b2 = y4[i + 2 * stride];
        float4 b3 = y4[i + 3 * stride];

        s += (a0.x > b0.x) ? (a0.x - b0.x) : 0.0f;  c += (a0.x > b0.x);
        s += (a0.y > b0.y) ? (a0.y - b0.y) : 0.0f;  c += (a0.y > b0.y);
        s += (a0.z > b0.z) ? (a0.z - b0.z) : 0.0f;  c += (a0.z > b0.z);
        s += (a0.w > b0.w) ? (a0.w - b0.w) : 0.0f;  c += (a0.w > b0.w);
        s += (a1.x > b1.x) ? (a1.x - b1.x) : 0.0f;  c += (a1.x > b1.x);
        s += (a1.y > b1.y) ? (a1.y - b1.y) : 0.0f;  c += (a1.y > b1.y);
        s += (a1.z > b1.z) ? (a1.z - b1.z) : 0.0f;  c += (a1.z > b1.z);
        s += (a1.w > b1.w) ? (a1.w - b1.w) : 0.0f;  c += (a1.w > b1.w);
        s += (a2.x > b2.x) ? (a2.x - b2.x) : 0.0f;  c += (a2.x > b2.x);
        s += (a2.y > b2.y) ? (a2.y - b2.y) : 0.0f;  c += (a2.y > b2.y);
        s += (a2.z > b2.z) ? (a2.z - b2.z) : 0.0f;  c += (a2.z > b2.z);
        s += (a2.w > b2.w) ? (a2.w - b2.w) : 0.0f;  c += (a2.w > b2.w);
        s += (a3.x > b3.x) ? (a3.x - b3.x) : 0.0f;  c += (a3.x > b3.x);
        s += (a3.y > b3.y) ? (a3.y - b3.y) : 0.0f;  c += (a3.y > b3.y);
        s += (a3.z > b3.z) ? (a3.z - b3.z) : 0.0f;  c += (a3.z > b3.z);
        s += (a3.w > b3.w) ? (a3.w - b3.w) : 0.0f;  c += (a3.w > b3.w);
    }
    for (; i < nvec; i += stride) {
        float4 a = x4[i];
        float4 b = y4[i];
        s += (a.x > b.x) ? (a.x - b.x) : 0.0f;  c += (a.x > b.x);
        s += (a.y > b.y) ? (a.y - b.y) : 0.0f;  c += (a.y > b.y);
        s += (a.z > b.z) ? (a.z - b.z) : 0.0f;  c += (a.z > b.z);
        s += (a.w > b.w) ? (a.w - b.w) : 0.0f;  c += (a.w > b.w);
    }
    // scalar tail (none for this shape)
    if (tid == 0) {
        for (long long j = nvec << 2; j < n; ++j) {
            float d = x[j] - y[j];
            if (x[j] > y[j]) { s += d; c += 1; }
        }
    }

    // wave-64 shuffle reduction
    #pragma unroll
    for (int off = 32; off > 0; off >>= 1) {
        s += __shfl_down(s, off, 64);
        c += __shfl_down(c, off, 64);
    }

    __shared__ float ss[NTHREADS / 64];
    __shared__ int   sc[NTHREADS / 64];
    int lane = threadIdx.x & 63;
    int wave = threadIdx.x >> 6;
    if (lane == 0) { ss[wave] = s; sc[wave] = c; }
    __syncthreads();
    if (threadIdx.x == 0) {
        float ts = 0.0f; int tc = 0;
        #pragma unroll
        for (int w = 0; w < NTHREADS / 64; ++w) { ts += ss[w]; tc += sc[w]; }
        psum[blockIdx.x] = ts;
        pcnt[blockIdx.x] = tc;
    }
}

__global__ __launch_bounds__(1024) void loss1_final(
    const float* __restrict__ psum, const int* __restrict__ pcnt,
    int nparts, float* __restrict__ out) {
    int tid = threadIdx.x;
    float s = 0.0f;
    int c = 0;
    for (int i = tid; i < nparts; i += 1024) {
        s += psum[i];
        c += pcnt[i];
    }
    #pragma unroll
    for (int off = 32; off > 0; off >>= 1) {
        s += __shfl_down(s, off, 64);
        c += __shfl_down(c, off, 64);
    }
    __shared__ float ss[16];
    __shared__ int   sc[16];
    int lane = tid & 63;
    int wave = tid >> 6;
    if (lane == 0) { ss[wave] = s; sc[wave] = c; }
    __syncthreads();
    if (tid == 0) {
        float ts = 0.0f; int tc = 0;
        #pragma unroll
        for (int w = 0; w < 16; ++w) { ts += ss[w]; tc += sc[w]; }
        out[0] = (tc > 0) ? (ts / (float)tc) : 0.0f;
    }
}

extern "C" void kernel_launch(void* const* d_in, const int* in_sizes, int n_in,
                              void* d_out, int out_size, void* d_ws, size_t ws_size,
                              hipStream_t stream) {
    const float* x = (const float*)d_in[0];
    const float* y = (const float*)d_in[1];
    long long n = (long long)in_sizes[0];

    float* psum = (float*)d_ws;
    int*   pcnt = (int*)((char*)d_ws + NBLOCKS * sizeof(float));

    loss1_partial<<<NBLOCKS, NTHREADS, 0, stream>>>(x, y, n, psum, pcnt);
    loss1_final<<<1, 1024, 0, stream>>>(psum, pcnt, NBLOCKS, (float*)d_out);
}

// Round 3
// 261.187 us; speedup vs baseline: 1.0599x; 1.0599x over previous
//
#include <hip/hip_runtime.h>

#define NBLOCKS 4096
#define NTHREADS 256
// Each block-tile: NTHREADS threads x 4 float4 = 1024 float4 = 16 KB per array.
#define TILE_V4 (NTHREADS * 4)

typedef float vf4 __attribute__((ext_vector_type(4)));

__global__ __launch_bounds__(NTHREADS) void loss1_partial(
    const float* __restrict__ x, const float* __restrict__ y,
    long long n, float* __restrict__ psum, int* __restrict__ pcnt) {
    const long long nvec = n >> 2;
    const long long ntiles = nvec / TILE_V4;   // full 16KB tiles
    const vf4* __restrict__ x4 = (const vf4*)x;
    const vf4* __restrict__ y4 = (const vf4*)y;

    float s = 0.0f;
    int c = 0;

    // Contiguous-tile sweep: per tile, the block reads 16KB of x as four
    // wave-contiguous 4KB batches, then 16KB of y. Avoids per-16B x/y
    // alternation (x,y are 2^27 B apart -> same L3 set + same HBM bank,
    // different row -> row-buffer thrash). x loads are nontemporal: zero
    // reuse, and normal fills evict the L3-resident y lines they alias.
    for (long long t = blockIdx.x; t < ntiles; t += gridDim.x) {
        long long p = t * TILE_V4 + threadIdx.x;
        vf4 a0 = __builtin_nontemporal_load(&x4[p]);
        vf4 a1 = __builtin_nontemporal_load(&x4[p + NTHREADS]);
        vf4 a2 = __builtin_nontemporal_load(&x4[p + 2 * NTHREADS]);
        vf4 a3 = __builtin_nontemporal_load(&x4[p + 3 * NTHREADS]);
        vf4 b0 = y4[p];
        vf4 b1 = y4[p + NTHREADS];
        vf4 b2 = y4[p + 2 * NTHREADS];
        vf4 b3 = y4[p + 3 * NTHREADS];

        #pragma unroll
        for (int k = 0; k < 4; ++k) {
            s += (a0[k] > b0[k]) ? (a0[k] - b0[k]) : 0.0f;  c += (a0[k] > b0[k]);
            s += (a1[k] > b1[k]) ? (a1[k] - b1[k]) : 0.0f;  c += (a1[k] > b1[k]);
            s += (a2[k] > b2[k]) ? (a2[k] - b2[k]) : 0.0f;  c += (a2[k] > b2[k]);
            s += (a3[k] > b3[k]) ? (a3[k] - b3[k]) : 0.0f;  c += (a3[k] > b3[k]);
        }
    }

    // float4 tail beyond the last full tile (none for this shape)
    {
        long long gtid = (long long)blockIdx.x * blockDim.x + threadIdx.x;
        long long gstride = (long long)gridDim.x * blockDim.x;
        for (long long i = ntiles * TILE_V4 + gtid; i < nvec; i += gstride) {
            vf4 a = x4[i];
            vf4 b = y4[i];
            #pragma unroll
            for (int k = 0; k < 4; ++k) {
                s += (a[k] > b[k]) ? (a[k] - b[k]) : 0.0f;  c += (a[k] > b[k]);
            }
        }
        // scalar tail for n % 4 (none for this shape)
        if (gtid == 0) {
            for (long long j = nvec << 2; j < n; ++j) {
                float d = x[j] - y[j];
                if (x[j] > y[j]) { s += d; c += 1; }
            }
        }
    }

    // wave-64 shuffle reduction
    #pragma unroll
    for (int off = 32; off > 0; off >>= 1) {
        s += __shfl_down(s, off, 64);
        c += __shfl_down(c, off, 64);
    }

    __shared__ float ss[NTHREADS / 64];
    __shared__ int   sc[NTHREADS / 64];
    int lane = threadIdx.x & 63;
    int wave = threadIdx.x >> 6;
    if (lane == 0) { ss[wave] = s; sc[wave] = c; }
    __syncthreads();
    if (threadIdx.x == 0) {
        float ts = 0.0f; int tc = 0;
        #pragma unroll
        for (int w = 0; w < NTHREADS / 64; ++w) { ts += ss[w]; tc += sc[w]; }
        psum[blockIdx.x] = ts;
        pcnt[blockIdx.x] = tc;
    }
}

__global__ __launch_bounds__(1024) void loss1_final(
    const float* __restrict__ psum, const int* __restrict__ pcnt,
    int nparts, float* __restrict__ out) {
    int tid = threadIdx.x;
    float s = 0.0f;
    int c = 0;
    for (int i = tid; i < nparts; i += 1024) {
        s += psum[i];
        c += pcnt[i];
    }
    #pragma unroll
    for (int off = 32; off > 0; off >>= 1) {
        s += __shfl_down(s, off, 64);
        c += __shfl_down(c, off, 64);
    }
    __shared__ float ss[16];
    __shared__ int   sc[16];
    int lane = tid & 63;
    int wave = tid >> 6;
    if (lane == 0) { ss[wave] = s; sc[wave] = c; }
    __syncthreads();
    if (tid == 0) {
        float ts = 0.0f; int tc = 0;
        #pragma unroll
        for (int w = 0; w < 16; ++w) { ts += ss[w]; tc += sc[w]; }
        out[0] = (tc > 0) ? (ts / (float)tc) : 0.0f;
    }
}

extern "C" void kernel_launch(void* const* d_in, const int* in_sizes, int n_in,
                              void* d_out, int out_size, void* d_ws, size_t ws_size,
                              hipStream_t stream) {
    const float* x = (const float*)d_in[0];
    const float* y = (const float*)d_in[1];
    long long n = (long long)in_sizes[0];

    float* psum = (float*)d_ws;
    int*   pcnt = (int*)((char*)d_ws + NBLOCKS * sizeof(float));

    loss1_partial<<<NBLOCKS, NTHREADS, 0, stream>>>(x, y, n, psum, pcnt);
    loss1_final<<<1, 1024, 0, stream>>>(psum, pcnt, NBLOCKS, (float*)d_out);
}